// Round 1
// baseline (1431.111 us; speedup 1.0000x reference)
//
#include <hip/hip_runtime.h>
#include <math.h>

#define TT 2048
#define CC 64
#define BB 32
#define PAD 512
#define LROW (TT + 2*PAD)   // 3072

// Gaussian taps: lengths 65,129,257,513,1025 at offsets 0,65,194,451,964 (total 1989)
__device__ float g_kern[1989];

__device__ __forceinline__ float fast_rcp(float x) { return __builtin_amdgcn_rcpf(x); }

// Abramowitz-Stegun 7.1.26, |abs err| < 1.5e-7
__device__ __forceinline__ float erf_fast(float u) {
  float au = fabsf(u);
  float t = fast_rcp(fmaf(0.3275911f, au, 1.0f));
  float p = fmaf(1.061405429f, t, -1.453152027f);
  p = fmaf(p, t, 1.421413741f);
  p = fmaf(p, t, -0.284496736f);
  p = fmaf(p, t, 0.254829592f);
  float r = fmaf(-p * t, __expf(-au * au), 1.0f);
  return copysignf(r, u);
}

__device__ __forceinline__ float gelu_f(float x) {
  return 0.5f * x * (1.0f + erf_fast(x * 0.70710678118654752f));
}

__global__ void init_gauss() {
  const int   R[5]   = {32, 64, 128, 256, 512};
  const float sig[5] = {8.f, 16.f, 32.f, 64.f, 128.f};
  const int   off[5] = {0, 65, 194, 451, 964};
  int s = threadIdx.x;
  if (s < 5) {
    double sum = 0.0;
    for (int i = 0; i <= 2 * R[s]; ++i) {
      float n = (float)(i - R[s]) / sig[s];
      float v = __expf(-0.5f * n * n);
      g_kern[off[s] + i] = v;
      sum += (double)v;
    }
    float inv = (float)(1.0 / (sum + 1e-12));
    for (int i = 0; i <= 2 * R[s]; ++i) g_kern[off[s] + i] *= inv;
  }
}

__launch_bounds__(256)
__global__ void fused_main(const float* __restrict__ x,
                           const float* __restrict__ W1, const float* __restrict__ b1,
                           const float* __restrict__ W2, const float* __restrict__ b2,
                           const float* __restrict__ W3, const float* __restrict__ b3,
                           float* __restrict__ out) {
  __shared__ float lds[LROW];          // reflect-padded x row
  __shared__ float wbuf[5 * TT];       // per-output softmax gate weights (per-thread scratch)

  const int blk = blockIdx.x;
  const int c = blk & (CC - 1);
  const int b = blk >> 6;
  const float* xrow = x + (size_t)b * TT * CC + c;

  // ---- stage reflect-padded row into LDS ----
  for (int i = threadIdx.x; i < LROW; i += 256) {
    int t = i - PAD;
    t = (t < 0) ? -t : t;
    t = (t >= TT) ? (2 * TT - 2 - t) : t;
    lds[i] = xrow[(size_t)t * CC];
  }
  __syncthreads();

  const int t0 = threadIdx.x * 8;

  // ======== Phase A: windowed stats + MLP + softmax -> gate weights ========
  #pragma unroll 1
  for (int i = 0; i < 8; ++i) {
    const int t = t0 + i;
    const float xv = lds[PAD + t];

    float sm = 0.f, sq = 0.f, scv = 0.f;
    #pragma unroll
    for (int j = 0; j < 16; ++j) {
      float v = lds[PAD + t - 7 + j];
      sm += v;
      sq  = fmaf(v, v, sq);
      scv = fmaf(v, (float)j - 7.5f, scv);
    }
    const float mean = sm * 0.0625f;
    const float ex2  = sq * 0.0625f;
    const float var  = fmaxf(ex2 - mean * mean, 0.f);
    const float slope = scv * (1.0f / 340.0f);   // t_var+EPS rounds to 340.0 in f32

    const float stdv = sqrtf(var + 1e-6f);
    float z = (xv - mean) * fast_rcp(stdv);
    z = fminf(fmaxf(z, -10.f), 10.f);
    const float lv = __logf(var + 1e-6f) * 0.1f;
    float ns = slope * fast_rcp(stdv + 1e-6f);
    ns = fminf(fmaxf(ns, -10.f), 10.f);

    // MLP: feats[3] -> h1[32] -> h2[32] (streamed) -> logits[5]
    float h1[32];
    #pragma unroll
    for (int h = 0; h < 32; ++h) {
      float p = b1[h];
      p = fmaf(W1[h * 3 + 0], z,  p);
      p = fmaf(W1[h * 3 + 1], lv, p);
      p = fmaf(W1[h * 3 + 2], ns, p);
      h1[h] = gelu_f(p);
    }
    float lg0 = b3[0], lg1 = b3[1], lg2 = b3[2], lg3 = b3[3], lg4 = b3[4];
    #pragma unroll 2
    for (int g = 0; g < 32; ++g) {
      const float* w2r = W2 + g * 32;
      float a = b2[g];
      #pragma unroll
      for (int h = 0; h < 32; ++h) a = fmaf(w2r[h], h1[h], a);
      float hv = gelu_f(a);
      lg0 = fmaf(W3[g],       hv, lg0);
      lg1 = fmaf(W3[32 + g],  hv, lg1);
      lg2 = fmaf(W3[64 + g],  hv, lg2);
      lg3 = fmaf(W3[96 + g],  hv, lg3);
      lg4 = fmaf(W3[128 + g], hv, lg4);
    }

    // softmax(logits / 0.7)
    const float m = fmaxf(fmaxf(fmaxf(lg0, lg1), fmaxf(lg2, lg3)), lg4);
    const float kT = 1.0f / 0.7f;
    float e0 = __expf((lg0 - m) * kT);
    float e1 = __expf((lg1 - m) * kT);
    float e2 = __expf((lg2 - m) * kT);
    float e3 = __expf((lg3 - m) * kT);
    float e4 = __expf((lg4 - m) * kT);
    const float rs = fast_rcp(e0 + e1 + e2 + e3 + e4);
    wbuf[0 * TT + t] = e0 * rs;
    wbuf[1 * TT + t] = e1 * rs;
    wbuf[2 * TT + t] = e2 * rs;
    wbuf[3 * TT + t] = e3 * rs;
    wbuf[4 * TT + t] = e4 * rs;
  }
  // wbuf entries are produced and consumed by the same thread -> no barrier needed

  // ======== Phase B: 5-scale Gaussian conv + gated combine ========
  const int Rs[5]   = {32, 64, 128, 256, 512};
  const int koff[5] = {0, 65, 194, 451, 964};

  float o[8];
  #pragma unroll
  for (int i = 0; i < 8; ++i) o[i] = 0.f;

  #pragma unroll
  for (int s = 0; s < 5; ++s) {
    const float* kp = g_kern + koff[s];
    const float* base = &lds[PAD + t0 - Rs[s]];
    const int L = 2 * Rs[s];

    float acc8[8];
    #pragma unroll
    for (int i = 0; i < 8; ++i) acc8[i] = 0.f;

    for (int j = 0; j < L; j += 8) {
      float4 v0 = *(const float4*)(base + j);
      float4 v1 = *(const float4*)(base + j + 4);
      float4 v2 = *(const float4*)(base + j + 8);
      float4 v3 = *(const float4*)(base + j + 12);
      float w[16];
      w[0] = v0.x; w[1] = v0.y; w[2]  = v0.z; w[3]  = v0.w;
      w[4] = v1.x; w[5] = v1.y; w[6]  = v1.z; w[7]  = v1.w;
      w[8] = v2.x; w[9] = v2.y; w[10] = v2.z; w[11] = v2.w;
      w[12] = v3.x; w[13] = v3.y; w[14] = v3.z; w[15] = v3.w;
      #pragma unroll
      for (int jj = 0; jj < 8; ++jj) {
        const float kk = kp[j + jj];
        #pragma unroll
        for (int i = 0; i < 8; ++i) acc8[i] = fmaf(kk, w[jj + i], acc8[i]);
      }
    }
    { // remainder tap d = L  (kernel length is 2R+1)
      const float kk = kp[L];
      float4 v0 = *(const float4*)(base + L);
      float4 v1 = *(const float4*)(base + L + 4);
      float r[8] = {v0.x, v0.y, v0.z, v0.w, v1.x, v1.y, v1.z, v1.w};
      #pragma unroll
      for (int i = 0; i < 8; ++i) acc8[i] = fmaf(kk, r[i], acc8[i]);
    }

    #pragma unroll
    for (int i = 0; i < 8; ++i) {
      const float wv = wbuf[s * TT + t0 + i];
      o[i] = fmaf(wv, acc8[i], o[i]);
    }
  }

  // ---- store ----
  #pragma unroll
  for (int i = 0; i < 8; ++i) {
    out[((size_t)b * TT + t0 + i) * CC + c] = o[i];
  }
}

extern "C" void kernel_launch(void* const* d_in, const int* in_sizes, int n_in,
                              void* d_out, int out_size, void* d_ws, size_t ws_size,
                              hipStream_t stream) {
  const float* x  = (const float*)d_in[0];
  const float* W1 = (const float*)d_in[1];
  const float* b1 = (const float*)d_in[2];
  const float* W2 = (const float*)d_in[3];
  const float* b2 = (const float*)d_in[4];
  const float* W3 = (const float*)d_in[5];
  const float* b3 = (const float*)d_in[6];
  float* outp = (float*)d_out;

  hipLaunchKernelGGL(init_gauss, dim3(1), dim3(64), 0, stream);
  hipLaunchKernelGGL(fused_main, dim3(BB * CC), dim3(256), 0, stream,
                     x, W1, b1, W2, b2, W3, b3, outp);
}

// Round 2
// 760.878 us; speedup vs baseline: 1.8809x; 1.8809x over previous
//
#include <hip/hip_runtime.h>
#include <math.h>

#define TT 2048
#define CC 64
#define BB 32
#define PAD 512
#define LROW (TT + 2*PAD)   // 3072 floats

// Gaussian taps, 16B-aligned per-scale offsets: lengths 65,129,257,513,1025
__device__ __align__(16) float g_kern[2016];

__device__ __forceinline__ float fast_rcp(float x) { return __builtin_amdgcn_rcpf(x); }

// 16B-granularity XOR swizzle: f in float4 units
__device__ __forceinline__ int swz16(int f) { return f ^ ((f >> 3) & 7); }
__device__ __forceinline__ int swz_byte(int e) {   // e in float units
  int f = e >> 2;
  return (swz16(f) << 4) | ((e & 3) << 2);
}

// Abramowitz-Stegun 7.1.26, |abs err| < 1.5e-7
__device__ __forceinline__ float erf_fast(float u) {
  float au = fabsf(u);
  float t = fast_rcp(fmaf(0.3275911f, au, 1.0f));
  float p = fmaf(1.061405429f, t, -1.453152027f);
  p = fmaf(p, t, 1.421413741f);
  p = fmaf(p, t, -0.284496736f);
  p = fmaf(p, t, 0.254829592f);
  float r = fmaf(-p * t, __expf(-au * au), 1.0f);
  return copysignf(r, u);
}

__device__ __forceinline__ float gelu_f(float x) {
  return 0.5f * x * (1.0f + erf_fast(x * 0.70710678118654752f));
}

__global__ void init_gauss() {
  const int   R[5]   = {32, 64, 128, 256, 512};
  const float sig[5] = {8.f, 16.f, 32.f, 64.f, 128.f};
  const int   off[5] = {0, 72, 208, 472, 984};
  int s = threadIdx.x;
  if (s < 5) {
    double sum = 0.0;
    for (int i = 0; i <= 2 * R[s]; ++i) {
      float n = (float)(i - R[s]) / sig[s];
      float v = __expf(-0.5f * n * n);
      g_kern[off[s] + i] = v;
      sum += (double)v;
    }
    float inv = (float)(1.0 / (sum + 1e-12));
    for (int i = 0; i <= 2 * R[s]; ++i) g_kern[off[s] + i] *= inv;
  }
}

__launch_bounds__(256, 3)
__global__ void fused_main(const float* __restrict__ x,
                           const float* __restrict__ W1, const float* __restrict__ b1,
                           const float* __restrict__ W2, const float* __restrict__ b2,
                           const float* __restrict__ W3, const float* __restrict__ b3,
                           float* __restrict__ out) {
  __shared__ float lds[LROW];       // swizzled reflect-padded x row
  __shared__ float wbuf[40 * 256];  // gate weights, [s*8+i][tid] lane-contiguous

  char* ldsb = (char*)lds;
  const int tid = threadIdx.x;
  const int blk = blockIdx.x;
  const int c = blk & (CC - 1);
  const int b = blk >> 6;
  const float* xrow = x + (size_t)b * TT * CC + c;

  // ---- stage reflect-padded row into swizzled LDS ----
  for (int i = tid; i < LROW; i += 256) {
    int t = i - PAD;
    t = (t < 0) ? -t : t;
    t = (t >= TT) ? (2 * TT - 2 - t) : t;
    *(float*)(ldsb + swz_byte(i)) = xrow[(size_t)t * CC];
  }
  __syncthreads();

  const int t0 = tid * 8;

  // ======== Phase A: stats from a 24-float register window ========
  float w24[24];
  {
    const int f0 = (PAD + t0 - 8) >> 2;   // 126 + 2*tid
    #pragma unroll
    for (int k = 0; k < 6; ++k) {
      float4 v = *(const float4*)(ldsb + (swz16(f0 + k) << 4));
      w24[4*k+0] = v.x; w24[4*k+1] = v.y; w24[4*k+2] = v.z; w24[4*k+3] = v.w;
    }
  }
  float zf[8], lvf[8], nsf[8];
  #pragma unroll
  for (int i = 0; i < 8; ++i) {
    float sm = 0.f, sq = 0.f, scv = 0.f;
    #pragma unroll
    for (int j = 0; j < 16; ++j) {
      float v = w24[i + 1 + j];           // x[t0+i-7+j]
      sm += v;
      sq  = fmaf(v, v, sq);
      scv = fmaf(v, (float)j - 7.5f, scv);
    }
    const float xv   = w24[i + 8];        // x[t0+i]
    const float mean = sm * 0.0625f;
    const float ex2  = sq * 0.0625f;
    const float var  = fmaxf(ex2 - mean * mean, 0.f);
    const float slope = scv * (1.0f / 340.0f);   // t_var+EPS == 340.0 in f32

    const float stdv = sqrtf(var + 1e-6f);
    float z = (xv - mean) * fast_rcp(stdv);
    zf[i] = fminf(fmaxf(z, -10.f), 10.f);
    lvf[i] = __logf(var + 1e-6f) * 0.1f;
    float ns = slope * fast_rcp(stdv + 1e-6f);
    nsf[i] = fminf(fmaxf(ns, -10.f), 10.f);
  }

  // ======== Phase A2: MLP + softmax -> gate weights (lane-contiguous wbuf) ====
  #pragma unroll 1
  for (int i = 0; i < 8; ++i) {
    float h1[32];
    #pragma unroll
    for (int h = 0; h < 32; ++h) {
      float p = b1[h];
      p = fmaf(W1[h * 3 + 0], zf[i],  p);
      p = fmaf(W1[h * 3 + 1], lvf[i], p);
      p = fmaf(W1[h * 3 + 2], nsf[i], p);
      h1[h] = gelu_f(p);
    }
    float lg0 = b3[0], lg1 = b3[1], lg2 = b3[2], lg3 = b3[3], lg4 = b3[4];
    #pragma unroll 2
    for (int g = 0; g < 32; ++g) {
      const float* w2r = W2 + g * 32;
      float a = b2[g];
      #pragma unroll
      for (int h = 0; h < 32; ++h) a = fmaf(w2r[h], h1[h], a);
      float hv = gelu_f(a);
      lg0 = fmaf(W3[g],       hv, lg0);
      lg1 = fmaf(W3[32 + g],  hv, lg1);
      lg2 = fmaf(W3[64 + g],  hv, lg2);
      lg3 = fmaf(W3[96 + g],  hv, lg3);
      lg4 = fmaf(W3[128 + g], hv, lg4);
    }

    const float m = fmaxf(fmaxf(fmaxf(lg0, lg1), fmaxf(lg2, lg3)), lg4);
    const float kT = 1.0f / 0.7f;
    float e0 = __expf((lg0 - m) * kT);
    float e1 = __expf((lg1 - m) * kT);
    float e2 = __expf((lg2 - m) * kT);
    float e3 = __expf((lg3 - m) * kT);
    float e4 = __expf((lg4 - m) * kT);
    const float rs = fast_rcp(e0 + e1 + e2 + e3 + e4);
    wbuf[(0 * 8 + i) * 256 + tid] = e0 * rs;
    wbuf[(1 * 8 + i) * 256 + tid] = e1 * rs;
    wbuf[(2 * 8 + i) * 256 + tid] = e2 * rs;
    wbuf[(3 * 8 + i) * 256 + tid] = e3 * rs;
    wbuf[(4 * 8 + i) * 256 + tid] = e4 * rs;
  }
  // wbuf produced & consumed by the same thread -> no barrier needed

  // ======== Phase B: 5-scale Gaussian conv (swizzled LDS) + gated combine ====
  float o[8];
  #pragma unroll
  for (int i = 0; i < 8; ++i) o[i] = 0.f;

  const int Rs[5]   = {32, 64, 128, 256, 512};
  const int koff[5] = {0, 72, 208, 472, 984};

  #pragma unroll
  for (int s = 0; s < 5; ++s) {
    const int R = Rs[s];
    const int L = 2 * R;
    const float* kp = g_kern + koff[s];
    const int fb = 128 + 2 * tid - (R >> 2);   // float4-unit base of window

    float a8[8];
    #pragma unroll
    for (int i = 0; i < 8; ++i) a8[i] = 0.f;

    for (int j = 0; j < L; j += 8) {
      float4 k0 = *(const float4*)(kp + j);
      float4 k1 = *(const float4*)(kp + j + 4);
      const int f = fb + (j >> 2);
      float4 v0 = *(const float4*)(ldsb + (swz16(f)     << 4));
      float4 v1 = *(const float4*)(ldsb + (swz16(f + 1) << 4));
      float4 v2 = *(const float4*)(ldsb + (swz16(f + 2) << 4));
      float4 v3 = *(const float4*)(ldsb + (swz16(f + 3) << 4));
      float w[16] = {v0.x, v0.y, v0.z, v0.w, v1.x, v1.y, v1.z, v1.w,
                     v2.x, v2.y, v2.z, v2.w, v3.x, v3.y, v3.z, v3.w};
      float kk[8] = {k0.x, k0.y, k0.z, k0.w, k1.x, k1.y, k1.z, k1.w};
      #pragma unroll
      for (int jj = 0; jj < 8; ++jj) {
        #pragma unroll
        for (int i = 0; i < 8; ++i) a8[i] = fmaf(kk[jj], w[jj + i], a8[i]);
      }
    }
    { // remainder tap d = L (kernel length 2R+1)
      const float kk = kp[L];
      const int f = fb + (L >> 2);
      float4 v0 = *(const float4*)(ldsb + (swz16(f)     << 4));
      float4 v1 = *(const float4*)(ldsb + (swz16(f + 1) << 4));
      float r[8] = {v0.x, v0.y, v0.z, v0.w, v1.x, v1.y, v1.z, v1.w};
      #pragma unroll
      for (int i = 0; i < 8; ++i) a8[i] = fmaf(kk, r[i], a8[i]);
    }

    #pragma unroll
    for (int i = 0; i < 8; ++i) {
      o[i] = fmaf(wbuf[(s * 8 + i) * 256 + tid], a8[i], o[i]);
    }
  }

  // ---- store ----
  #pragma unroll
  for (int i = 0; i < 8; ++i) {
    out[((size_t)b * TT + t0 + i) * CC + c] = o[i];
  }
}

extern "C" void kernel_launch(void* const* d_in, const int* in_sizes, int n_in,
                              void* d_out, int out_size, void* d_ws, size_t ws_size,
                              hipStream_t stream) {
  const float* x  = (const float*)d_in[0];
  const float* W1 = (const float*)d_in[1];
  const float* b1 = (const float*)d_in[2];
  const float* W2 = (const float*)d_in[3];
  const float* b2 = (const float*)d_in[4];
  const float* W3 = (const float*)d_in[5];
  const float* b3 = (const float*)d_in[6];
  float* outp = (float*)d_out;

  hipLaunchKernelGGL(init_gauss, dim3(1), dim3(64), 0, stream);
  hipLaunchKernelGGL(fused_main, dim3(BB * CC), dim3(256), 0, stream,
                     x, W1, b1, W2, b2, W3, b3, outp);
}

// Round 3
// 429.508 us; speedup vs baseline: 3.3320x; 1.7715x over previous
//
#include <hip/hip_runtime.h>
#include <math.h>

#define TT 2048
#define CC 64
#define BB 32
#define PAD 512
#define ROWL 3136          // padded bf16 row length (window + slack)

typedef __attribute__((ext_vector_type(8))) short short8;
typedef __attribute__((ext_vector_type(4))) float float4v;

// Toeplitz A-fragment tables: 67 K-steps x 64 lanes x 8 bf16 (hi/lo split)
#define NSTEPS 67
__device__ unsigned short g_afrag_hi[NSTEPS * 64 * 8];
__device__ unsigned short g_afrag_lo[NSTEPS * 64 * 8];

__device__ __forceinline__ float fast_rcp(float x) { return __builtin_amdgcn_rcpf(x); }

__device__ __forceinline__ unsigned short f2bf(float x) {  // RNE bf16 round
  union { float f; unsigned u; } v; v.f = x;
  unsigned r = (v.u + 0x7FFFu + ((v.u >> 16) & 1u)) >> 16;
  return (unsigned short)r;
}
__device__ __forceinline__ float bf2f(unsigned short u) {
  union { unsigned u32; float f; } v; v.u32 = ((unsigned)u) << 16; return v.f;
}

// Abramowitz-Stegun 7.1.26, |abs err| < 1.5e-7
__device__ __forceinline__ float erf_fast(float u) {
  float au = fabsf(u);
  float t = fast_rcp(fmaf(0.3275911f, au, 1.0f));
  float p = fmaf(1.061405429f, t, -1.453152027f);
  p = fmaf(p, t, 1.421413741f);
  p = fmaf(p, t, -0.284496736f);
  p = fmaf(p, t, 0.254829592f);
  float r = fmaf(-p * t, __expf(-au * au), 1.0f);
  return copysignf(r, u);
}
__device__ __forceinline__ float gelu_f(float x) {
  return 0.5f * x * (1.0f + erf_fast(x * 0.70710678118654752f));
}

// ---- init: taps + per-lane Toeplitz A-fragments (hi/lo bf16) ----
__global__ void init_frag() {
  __shared__ float ktap[2016];
  __shared__ double ssum[5];
  const int   Rr[5]  = {32, 64, 128, 256, 512};
  const float sg[5]  = {8.f, 16.f, 32.f, 64.f, 128.f};
  const int   off[5] = {0, 72, 208, 472, 984};
  const int tid = threadIdx.x;

  for (int idx = tid; idx < 2016; idx += 256) {
    int s = (idx < 72) ? 0 : (idx < 208) ? 1 : (idx < 472) ? 2 : (idx < 984) ? 3 : 4;
    int d = idx - off[s];
    float v = 0.f;
    if (d <= 2 * Rr[s]) {
      float n = (float)(d - Rr[s]) / sg[s];
      v = __expf(-0.5f * n * n);
    }
    ktap[idx] = v;
  }
  __syncthreads();
  if (tid < 5) {
    double sum = 0.0;
    for (int d = 0; d <= 2 * Rr[tid]; ++d) sum += (double)ktap[off[tid] + d];
    ssum[tid] = 1.0 / (sum + 1e-12);
  }
  __syncthreads();
  for (int idx = tid; idx < 2016; idx += 256) {
    int s = (idx < 72) ? 0 : (idx < 208) ? 1 : (idx < 472) ? 2 : (idx < 984) ? 3 : 4;
    ktap[idx] *= (float)ssum[s];
  }
  __syncthreads();

  // A[i,j] = ktap[j - i] (zero outside band); lane: row i = lane&15, k = 32*st + 8*(lane>>4) + e
  const int cum[5] = {0, 3, 8, 17, 34};
  for (int e = tid; e < NSTEPS * 64; e += 256) {
    int stg = e >> 6, lane = e & 63;
    int s = (stg < 3) ? 0 : (stg < 8) ? 1 : (stg < 17) ? 2 : (stg < 34) ? 3 : 4;
    int st = stg - cum[s];
    int i = lane & 15, h = lane >> 4;
    for (int e2 = 0; e2 < 8; ++e2) {
      int d = st * 32 + 8 * h + e2 - i;
      float v = (d >= 0 && d <= 2 * Rr[s]) ? ktap[off[s] + d] : 0.f;
      unsigned short hi = f2bf(v);
      g_afrag_hi[e * 8 + e2] = hi;
      g_afrag_lo[e * 8 + e2] = f2bf(v - bf2f(hi));
    }
  }
}

__launch_bounds__(256, 3)
__global__ void fused_main(const float* __restrict__ x,
                           const float* __restrict__ W1, const float* __restrict__ b1,
                           const float* __restrict__ W2, const float* __restrict__ b2,
                           const float* __restrict__ W3, const float* __restrict__ b3,
                           float* __restrict__ out) {
  __shared__ unsigned short row_hi[ROWL];
  __shared__ unsigned short row_lo[ROWL];
  __shared__ float gbuf[8][5][16][16];   // [chunk][scale][t%16][(t/16)%16]

  const int tid = threadIdx.x;
  const int c = blockIdx.x & (CC - 1);
  const int b = blockIdx.x >> 6;
  const float* xrow = x + (size_t)b * TT * CC + c;

  // ---- stage reflect-padded row as hi/lo bf16 ----
  for (int i2 = tid; i2 < ROWL; i2 += 256) {
    int t = i2 - PAD;
    t = (t < 0) ? -t : t;
    t = (t >= TT) ? (2 * TT - 2 - t) : t;
    float xv = xrow[(size_t)t * CC];
    unsigned short hi = f2bf(xv);
    row_hi[i2] = hi;
    row_lo[i2] = f2bf(xv - bf2f(hi));
  }
  __syncthreads();

  const int t0 = tid * 8;

  // ======== Phase A: stats (exact fp32 via hi+lo) + MLP + softmax ========
  float w24[24];
  {
    const unsigned short* ph = &row_hi[PAD + t0 - 8];
    const unsigned short* pl = &row_lo[PAD + t0 - 8];
    unsigned hw[12], lw[12];
    *(uint4*)&hw[0] = *(const uint4*)ph;
    *(uint4*)&hw[4] = *(const uint4*)(ph + 8);
    *(uint4*)&hw[8] = *(const uint4*)(ph + 16);
    *(uint4*)&lw[0] = *(const uint4*)pl;
    *(uint4*)&lw[4] = *(const uint4*)(pl + 8);
    *(uint4*)&lw[8] = *(const uint4*)(pl + 16);
    #pragma unroll
    for (int m = 0; m < 12; ++m) {
      union { unsigned u; float f; } a, bb, cc2, dd;
      a.u  = (hw[m] & 0xFFFFu) << 16;  bb.u = hw[m] & 0xFFFF0000u;
      cc2.u = (lw[m] & 0xFFFFu) << 16; dd.u = lw[m] & 0xFFFF0000u;
      w24[2 * m]     = a.f + cc2.f;
      w24[2 * m + 1] = bb.f + dd.f;
    }
  }

  float zf[8], lvf[8], nsf[8];
  #pragma unroll
  for (int i = 0; i < 8; ++i) {
    float sm = 0.f, sq = 0.f, scv = 0.f;
    #pragma unroll
    for (int j = 0; j < 16; ++j) {
      float v = w24[i + 1 + j];
      sm += v;
      sq  = fmaf(v, v, sq);
      scv = fmaf(v, (float)j - 7.5f, scv);
    }
    const float xv   = w24[i + 8];
    const float mean = sm * 0.0625f;
    const float ex2  = sq * 0.0625f;
    const float var  = fmaxf(ex2 - mean * mean, 0.f);
    const float slope = scv * (1.0f / 340.0f);

    const float stdv = sqrtf(var + 1e-6f);
    float z = (xv - mean) * fast_rcp(stdv);
    zf[i] = fminf(fmaxf(z, -10.f), 10.f);
    lvf[i] = __logf(var + 1e-6f) * 0.1f;
    float ns = slope * fast_rcp(stdv + 1e-6f);
    nsf[i] = fminf(fmaxf(ns, -10.f), 10.f);
  }

  #pragma unroll 1
  for (int i = 0; i < 8; ++i) {
    float h1[32];
    #pragma unroll
    for (int h = 0; h < 32; ++h) {
      float p = b1[h];
      p = fmaf(W1[h * 3 + 0], zf[i],  p);
      p = fmaf(W1[h * 3 + 1], lvf[i], p);
      p = fmaf(W1[h * 3 + 2], nsf[i], p);
      h1[h] = gelu_f(p);
    }
    float lg0 = b3[0], lg1 = b3[1], lg2 = b3[2], lg3 = b3[3], lg4 = b3[4];
    #pragma unroll 2
    for (int g = 0; g < 32; ++g) {
      const float* w2r = W2 + g * 32;
      float a = b2[g];
      #pragma unroll
      for (int h = 0; h < 32; ++h) a = fmaf(w2r[h], h1[h], a);
      float hv = gelu_f(a);
      lg0 = fmaf(W3[g],       hv, lg0);
      lg1 = fmaf(W3[32 + g],  hv, lg1);
      lg2 = fmaf(W3[64 + g],  hv, lg2);
      lg3 = fmaf(W3[96 + g],  hv, lg3);
      lg4 = fmaf(W3[128 + g], hv, lg4);
    }

    const float m = fmaxf(fmaxf(fmaxf(lg0, lg1), fmaxf(lg2, lg3)), lg4);
    const float kT = 1.0f / 0.7f;
    float e0 = __expf((lg0 - m) * kT);
    float e1 = __expf((lg1 - m) * kT);
    float e2 = __expf((lg2 - m) * kT);
    float e3 = __expf((lg3 - m) * kT);
    float e4 = __expf((lg4 - m) * kT);
    const float rs = fast_rcp(e0 + e1 + e2 + e3 + e4);

    const int t = t0 + i;
    const int ch = t >> 8, rr = t & 15, pp = (t >> 4) & 15;
    gbuf[ch][0][rr][pp] = e0 * rs;
    gbuf[ch][1][rr][pp] = e1 * rs;
    gbuf[ch][2][rr][pp] = e2 * rs;
    gbuf[ch][3][rr][pp] = e3 * rs;
    gbuf[ch][4][rr][pp] = e4 * rs;
  }
  __syncthreads();

  // ======== Phase B: Toeplitz-MFMA conv (3-pass hi/lo) + gated combine ====
  const int wv = tid >> 6, lane = tid & 63;
  const int h = lane >> 4, p = lane & 15;
  const int ch0 = 2 * wv, ch1 = 2 * wv + 1;

  const int Rs[5]    = {32, 64, 128, 256, 512};
  const int steps[5] = {3, 5, 9, 17, 33};
  const int cum[5]   = {0, 3, 8, 17, 34};

  float4v o0 = {0.f, 0.f, 0.f, 0.f}, o1 = {0.f, 0.f, 0.f, 0.f};

  #pragma unroll 1
  for (int s = 0; s < 5; ++s) {
    float4v a0 = {0.f, 0.f, 0.f, 0.f}, a1 = {0.f, 0.f, 0.f, 0.f};
    const int eb0 = PAD + 256 * ch0 - Rs[s] + 16 * p + 8 * h;
    const int eb1 = eb0 + 256;
    const unsigned short* ahb = g_afrag_hi + (size_t)cum[s] * 512 + lane * 8;
    const unsigned short* alb = g_afrag_lo + (size_t)cum[s] * 512 + lane * 8;

    for (int st = 0; st < steps[s]; ++st) {
      short8 kh = *(const short8*)(ahb + st * 512);
      short8 kl = *(const short8*)(alb + st * 512);
      short8 b0h = *(const short8*)(&row_hi[eb0 + st * 32]);
      short8 b0l = *(const short8*)(&row_lo[eb0 + st * 32]);
      short8 b1h = *(const short8*)(&row_hi[eb1 + st * 32]);
      short8 b1l = *(const short8*)(&row_lo[eb1 + st * 32]);
      a0 = __builtin_amdgcn_mfma_f32_16x16x32_bf16(kh, b0h, a0, 0, 0, 0);
      a0 = __builtin_amdgcn_mfma_f32_16x16x32_bf16(kh, b0l, a0, 0, 0, 0);
      a0 = __builtin_amdgcn_mfma_f32_16x16x32_bf16(kl, b0h, a0, 0, 0, 0);
      a1 = __builtin_amdgcn_mfma_f32_16x16x32_bf16(kh, b1h, a1, 0, 0, 0);
      a1 = __builtin_amdgcn_mfma_f32_16x16x32_bf16(kh, b1l, a1, 0, 0, 0);
      a1 = __builtin_amdgcn_mfma_f32_16x16x32_bf16(kl, b1h, a1, 0, 0, 0);
    }
    #pragma unroll
    for (int r = 0; r < 4; ++r) {
      o0[r] = fmaf(gbuf[ch0][s][4 * h + r][p], a0[r], o0[r]);
      o1[r] = fmaf(gbuf[ch1][s][4 * h + r][p], a1[r], o1[r]);
    }
  }

  // ---- store ----
  const size_t obase = (size_t)b * TT * CC + c;
  #pragma unroll
  for (int r = 0; r < 4; ++r) {
    out[obase + (size_t)(256 * ch0 + 16 * p + 4 * h + r) * CC] = o0[r];
    out[obase + (size_t)(256 * ch1 + 16 * p + 4 * h + r) * CC] = o1[r];
  }
}

extern "C" void kernel_launch(void* const* d_in, const int* in_sizes, int n_in,
                              void* d_out, int out_size, void* d_ws, size_t ws_size,
                              hipStream_t stream) {
  const float* x  = (const float*)d_in[0];
  const float* W1 = (const float*)d_in[1];
  const float* b1 = (const float*)d_in[2];
  const float* W2 = (const float*)d_in[3];
  const float* b2 = (const float*)d_in[4];
  const float* W3 = (const float*)d_in[5];
  const float* b3 = (const float*)d_in[6];
  float* outp = (float*)d_out;

  hipLaunchKernelGGL(init_frag, dim3(1), dim3(256), 0, stream);
  hipLaunchKernelGGL(fused_main, dim3(BB * CC), dim3(256), 0, stream,
                     x, W1, b1, W2, b2, W3, b3, outp);
}

// Round 4
// 320.587 us; speedup vs baseline: 4.4640x; 1.3398x over previous
//
#include <hip/hip_runtime.h>
#include <hip/hip_fp16.h>
#include <math.h>

#define TT 2048
#define CC 64
#define BB 32
#define PAD 512
#define ROWL 3136          // padded bf16/f32 row length

typedef __attribute__((ext_vector_type(8))) short short8;
typedef __attribute__((ext_vector_type(4))) float float4v;

// Toeplitz A-fragment tables: 67 K-steps x 64 lanes x 8 bf16 (hi/lo split)
#define NSTEPS 67
__device__ unsigned short g_afrag_hi[NSTEPS * 64 * 8];
__device__ unsigned short g_afrag_lo[NSTEPS * 64 * 8];
// W2 A-fragments: 2 g-tiles x 64 lanes x 8 bf16 (hi/lo)
__device__ unsigned short g_w2frag_hi[2 * 64 * 8];
__device__ unsigned short g_w2frag_lo[2 * 64 * 8];

__device__ __forceinline__ float fast_rcp(float x) { return __builtin_amdgcn_rcpf(x); }

__device__ __forceinline__ unsigned short f2bf(float x) {  // RNE bf16 round
  union { float f; unsigned u; } v; v.f = x;
  unsigned r = (v.u + 0x7FFFu + ((v.u >> 16) & 1u)) >> 16;
  return (unsigned short)r;
}
__device__ __forceinline__ float bf2f(unsigned short u) {
  union { unsigned u32; float f; } v; v.u32 = ((unsigned)u) << 16; return v.f;
}

// Abramowitz-Stegun 7.1.26, |abs err| < 1.5e-7
__device__ __forceinline__ float erf_fast(float u) {
  float au = fabsf(u);
  float t = fast_rcp(fmaf(0.3275911f, au, 1.0f));
  float p = fmaf(1.061405429f, t, -1.453152027f);
  p = fmaf(p, t, 1.421413741f);
  p = fmaf(p, t, -0.284496736f);
  p = fmaf(p, t, 0.254829592f);
  float r = fmaf(-p * t, __expf(-au * au), 1.0f);
  return copysignf(r, u);
}
__device__ __forceinline__ float gelu_f(float x) {
  return 0.5f * x * (1.0f + erf_fast(x * 0.70710678118654752f));
}

// ---- init: Gaussian taps + Toeplitz frags + W2 frags ----
__global__ void init_frag(const float* __restrict__ W2) {
  __shared__ float ktap[2016];
  __shared__ double ssum[5];
  const int   Rr[5]  = {32, 64, 128, 256, 512};
  const float sg[5]  = {8.f, 16.f, 32.f, 64.f, 128.f};
  const int   off[5] = {0, 72, 208, 472, 984};
  const int tid = threadIdx.x;

  for (int idx = tid; idx < 2016; idx += 256) {
    int s = (idx < 72) ? 0 : (idx < 208) ? 1 : (idx < 472) ? 2 : (idx < 984) ? 3 : 4;
    int d = idx - off[s];
    float v = 0.f;
    if (d <= 2 * Rr[s]) {
      float n = (float)(d - Rr[s]) / sg[s];
      v = __expf(-0.5f * n * n);
    }
    ktap[idx] = v;
  }
  __syncthreads();
  if (tid < 5) {
    double sum = 0.0;
    for (int d = 0; d <= 2 * Rr[tid]; ++d) sum += (double)ktap[off[tid] + d];
    ssum[tid] = 1.0 / (sum + 1e-12);
  }
  __syncthreads();
  for (int idx = tid; idx < 2016; idx += 256) {
    int s = (idx < 72) ? 0 : (idx < 208) ? 1 : (idx < 472) ? 2 : (idx < 984) ? 3 : 4;
    ktap[idx] *= (float)ssum[s];
  }
  __syncthreads();

  const int cum[5] = {0, 3, 8, 17, 34};
  for (int e = tid; e < NSTEPS * 64; e += 256) {
    int stg = e >> 6, lane = e & 63;
    int s = (stg < 3) ? 0 : (stg < 8) ? 1 : (stg < 17) ? 2 : (stg < 34) ? 3 : 4;
    int st = stg - cum[s];
    int i = lane & 15, h = lane >> 4;
    for (int e2 = 0; e2 < 8; ++e2) {
      int d = st * 32 + 8 * h + e2 - i;
      float v = (d >= 0 && d <= 2 * Rr[s]) ? ktap[off[s] + d] : 0.f;
      unsigned short hi = f2bf(v);
      g_afrag_hi[e * 8 + e2] = hi;
      g_afrag_lo[e * 8 + e2] = f2bf(v - bf2f(hi));
    }
  }
  // W2 fragments: frag[gt][lane][e2] = W2[16gt + (lane&15)][8*(lane>>4) + e2]
  for (int e = tid; e < 2 * 64; e += 256) {
    int gt = e >> 6, lane = e & 63;
    int g = 16 * gt + (lane & 15), hbase = 8 * (lane >> 4);
    for (int e2 = 0; e2 < 8; ++e2) {
      float v = W2[g * 32 + hbase + e2];
      unsigned short hi = f2bf(v);
      g_w2frag_hi[e * 8 + e2] = hi;
      g_w2frag_lo[e * 8 + e2] = f2bf(v - bf2f(hi));
    }
  }
}

__launch_bounds__(256, 3)
__global__ void fused_main(const float* __restrict__ x,
                           const float* __restrict__ W1, const float* __restrict__ b1,
                           const float* __restrict__ W2, const float* __restrict__ b2,
                           const float* __restrict__ W3, const float* __restrict__ b3,
                           float* __restrict__ out) {
  __shared__ float row_f32[ROWL];
  __shared__ unsigned short row_hi[ROWL];
  __shared__ unsigned short row_lo[ROWL];
  __shared__ __half gbuf[8][5][16][20];   // gates; s=0..2 aliased as feats A1->A2

  const int tid = threadIdx.x;
  const int c = blockIdx.x & (CC - 1);
  const int b = blockIdx.x >> 6;
  const float* xrow = x + (size_t)b * TT * CC + c;

  // ---- stage reflect-padded row: f32 + bf16 hi/lo ----
  for (int i2 = tid; i2 < ROWL; i2 += 256) {
    int t = i2 - PAD;
    t = (t < 0) ? -t : t;
    t = (t >= TT) ? (2 * TT - 2 - t) : t;
    float xv = xrow[(size_t)t * CC];
    row_f32[i2] = xv;
    unsigned short hi = f2bf(xv);
    row_hi[i2] = hi;
    row_lo[i2] = f2bf(xv - bf2f(hi));
  }
  __syncthreads();

  const int t0 = tid * 8;
  const int lane = tid & 63;
  const int wvi = tid >> 6;

  // ======== Phase A1: per-thread stats -> feats (to gbuf alias slots) ========
  {
    float w24[24];
    const float* wp = &row_f32[PAD + t0 - 8];
    #pragma unroll
    for (int k = 0; k < 6; ++k) {
      float4v v = *(const float4v*)(wp + 4 * k);
      w24[4*k] = v[0]; w24[4*k+1] = v[1]; w24[4*k+2] = v[2]; w24[4*k+3] = v[3];
    }
    #pragma unroll
    for (int i = 0; i < 8; ++i) {
      float sm = 0.f, sq = 0.f, scv = 0.f;
      #pragma unroll
      for (int j = 0; j < 16; ++j) {
        float v = w24[i + 1 + j];
        sm += v;
        sq  = fmaf(v, v, sq);
        scv = fmaf(v, (float)j - 7.5f, scv);
      }
      const float xv   = w24[i + 8];
      const float mean = sm * 0.0625f;
      const float ex2  = sq * 0.0625f;
      const float var  = fmaxf(ex2 - mean * mean, 0.f);
      const float slope = scv * (1.0f / 340.0f);
      const float stdv = sqrtf(var + 1e-6f);
      float z = (xv - mean) * fast_rcp(stdv);
      z = fminf(fmaxf(z, -10.f), 10.f);
      float lv = __logf(var + 1e-6f) * 0.1f;
      float ns = slope * fast_rcp(stdv + 1e-6f);
      ns = fminf(fmaxf(ns, -10.f), 10.f);

      const int e = t0 + i;
      const int ch = e >> 8, rr = e & 15, pp = (e >> 4) & 15;
      gbuf[ch][0][rr][pp] = __float2half(z);
      gbuf[ch][1][rr][pp] = __float2half(lv);
      gbuf[ch][2][rr][pp] = __float2half(ns);
    }
  }

  // ======== Phase A2: wave-wide MLP via MFMA ========
  {
    const int kg = lane >> 4;        // k-group for B-frag / layer-1 slice
    const int hq = lane >> 4;        // row-quarter for C-frag
    const int m  = lane & 15;        // element column

    // loop-invariant weight slices
    short8 w2h0 = *(const short8*)(g_w2frag_hi + (0 * 64 + lane) * 8);
    short8 w2l0 = *(const short8*)(g_w2frag_lo + (0 * 64 + lane) * 8);
    short8 w2h1 = *(const short8*)(g_w2frag_hi + (1 * 64 + lane) * 8);
    short8 w2l1 = *(const short8*)(g_w2frag_lo + (1 * 64 + lane) * 8);
    float4v w1q[6], b1q2[2], b2a, b2b, w3A[5], w3B[5];
    #pragma unroll
    for (int k = 0; k < 6; ++k) w1q[k] = *(const float4v*)(W1 + 24 * kg + 4 * k);
    b1q2[0] = *(const float4v*)(b1 + 8 * kg);
    b1q2[1] = *(const float4v*)(b1 + 8 * kg + 4);
    b2a = *(const float4v*)(b2 + 4 * hq);
    b2b = *(const float4v*)(b2 + 16 + 4 * hq);
    #pragma unroll
    for (int k = 0; k < 5; ++k) {
      w3A[k] = *(const float4v*)(W3 + 32 * k + 4 * hq);
      w3B[k] = *(const float4v*)(W3 + 32 * k + 16 + 4 * hq);
    }
    const float b30 = b3[0], b31 = b3[1], b32 = b3[2], b33 = b3[3], b34 = b3[4];

    #pragma unroll 1
    for (int j = 0; j < 32; ++j) {
      const int ch = 2 * wvi + (j >> 4);
      const int pp = j & 15;

      // features of column element (read other lanes' A1 output)
      float z  = __half2float(gbuf[ch][0][m][pp]);
      float lv = __half2float(gbuf[ch][1][m][pp]);
      float ns = __half2float(gbuf[ch][2][m][pp]);

      // layer 1 in B-fragment layout: 8 neurons (k = 8*kg + e2) of column m
      short8 bfr;
      #pragma unroll
      for (int e2 = 0; e2 < 8; ++e2) {
        float p = b1q2[e2 >> 2][e2 & 3];
        p = fmaf(w1q[(3*e2)   >> 2][(3*e2)   & 3], z,  p);
        p = fmaf(w1q[(3*e2+1) >> 2][(3*e2+1) & 3], lv, p);
        p = fmaf(w1q[(3*e2+2) >> 2][(3*e2+2) & 3], ns, p);
        bfr[e2] = (short)f2bf(gelu_f(p));
      }

      // layer 2: h2pre = W2 * h1  (2 g-tiles, W2 hi/lo 2-pass)
      float4v acc0 = {0.f,0.f,0.f,0.f}, acc1 = {0.f,0.f,0.f,0.f};
      acc0 = __builtin_amdgcn_mfma_f32_16x16x32_bf16(w2h0, bfr, acc0, 0, 0, 0);
      acc0 = __builtin_amdgcn_mfma_f32_16x16x32_bf16(w2l0, bfr, acc0, 0, 0, 0);
      acc1 = __builtin_amdgcn_mfma_f32_16x16x32_bf16(w2h1, bfr, acc1, 0, 0, 0);
      acc1 = __builtin_amdgcn_mfma_f32_16x16x32_bf16(w2l1, bfr, acc1, 0, 0, 0);

      // bias + GELU + W3 partial dot (rows g = 16gt + 4hq + r)
      float lg0 = 0.f, lg1 = 0.f, lg2 = 0.f, lg3 = 0.f, lg4 = 0.f;
      #pragma unroll
      for (int r = 0; r < 4; ++r) {
        float ha = gelu_f(acc0[r] + b2a[r]);
        float hb = gelu_f(acc1[r] + b2b[r]);
        lg0 = fmaf(w3A[0][r], ha, lg0); lg0 = fmaf(w3B[0][r], hb, lg0);
        lg1 = fmaf(w3A[1][r], ha, lg1); lg1 = fmaf(w3B[1][r], hb, lg1);
        lg2 = fmaf(w3A[2][r], ha, lg2); lg2 = fmaf(w3B[2][r], hb, lg2);
        lg3 = fmaf(w3A[3][r], ha, lg3); lg3 = fmaf(w3B[3][r], hb, lg3);
        lg4 = fmaf(w3A[4][r], ha, lg4); lg4 = fmaf(w3B[4][r], hb, lg4);
      }
      // reduce across the 4 row-quarters (lanes m, m+16, m+32, m+48)
      lg0 += __shfl_xor(lg0, 16); lg0 += __shfl_xor(lg0, 32);
      lg1 += __shfl_xor(lg1, 16); lg1 += __shfl_xor(lg1, 32);
      lg2 += __shfl_xor(lg2, 16); lg2 += __shfl_xor(lg2, 32);
      lg3 += __shfl_xor(lg3, 16); lg3 += __shfl_xor(lg3, 32);
      lg4 += __shfl_xor(lg4, 16); lg4 += __shfl_xor(lg4, 32);
      lg0 += b30; lg1 += b31; lg2 += b32; lg3 += b33; lg4 += b34;

      // softmax(logits/0.7)
      const float mx = fmaxf(fmaxf(fmaxf(lg0, lg1), fmaxf(lg2, lg3)), lg4);
      const float kT = 1.0f / 0.7f;
      float e0 = __expf((lg0 - mx) * kT);
      float e1 = __expf((lg1 - mx) * kT);
      float e2 = __expf((lg2 - mx) * kT);
      float e3 = __expf((lg3 - mx) * kT);
      float e4 = __expf((lg4 - mx) * kT);
      const float rs = fast_rcp(e0 + e1 + e2 + e3 + e4);
      if ((lane & 48) == 0) {   // one writer per element (overwrites feat slots)
        gbuf[ch][0][m][pp] = __float2half(e0 * rs);
        gbuf[ch][1][m][pp] = __float2half(e1 * rs);
        gbuf[ch][2][m][pp] = __float2half(e2 * rs);
        gbuf[ch][3][m][pp] = __float2half(e3 * rs);
        gbuf[ch][4][m][pp] = __float2half(e4 * rs);
      }
    }
  }
  // gates produced & consumed by the same wave -> no barrier needed

  // ======== Phase B: Toeplitz-MFMA conv (3-pass hi/lo) + gated combine ====
  {
    const int hq = lane >> 4, p = lane & 15;
    const int ch0 = 2 * wvi, ch1 = 2 * wvi + 1;

    const int Rs[5]    = {32, 64, 128, 256, 512};
    const int steps[5] = {3, 5, 9, 17, 33};
    const int cum[5]   = {0, 3, 8, 17, 34};

    float4v o0 = {0.f,0.f,0.f,0.f}, o1 = {0.f,0.f,0.f,0.f};

    #pragma unroll 1
    for (int s = 0; s < 5; ++s) {
      float4v a0 = {0.f,0.f,0.f,0.f}, a1 = {0.f,0.f,0.f,0.f};
      const int eb0 = PAD + 256 * ch0 - Rs[s] + 16 * p + 8 * hq;
      const int eb1 = eb0 + 256;
      const unsigned short* ahb = g_afrag_hi + (size_t)cum[s] * 512 + lane * 8;
      const unsigned short* alb = g_afrag_lo + (size_t)cum[s] * 512 + lane * 8;

      for (int st = 0; st < steps[s]; ++st) {
        short8 kh = *(const short8*)(ahb + st * 512);
        short8 kl = *(const short8*)(alb + st * 512);
        short8 b0h = *(const short8*)(&row_hi[eb0 + st * 32]);
        short8 b0l = *(const short8*)(&row_lo[eb0 + st * 32]);
        short8 b1h = *(const short8*)(&row_hi[eb1 + st * 32]);
        short8 b1l = *(const short8*)(&row_lo[eb1 + st * 32]);
        a0 = __builtin_amdgcn_mfma_f32_16x16x32_bf16(kh, b0h, a0, 0, 0, 0);
        a0 = __builtin_amdgcn_mfma_f32_16x16x32_bf16(kh, b0l, a0, 0, 0, 0);
        a0 = __builtin_amdgcn_mfma_f32_16x16x32_bf16(kl, b0h, a0, 0, 0, 0);
        a1 = __builtin_amdgcn_mfma_f32_16x16x32_bf16(kh, b1h, a1, 0, 0, 0);
        a1 = __builtin_amdgcn_mfma_f32_16x16x32_bf16(kh, b1l, a1, 0, 0, 0);
        a1 = __builtin_amdgcn_mfma_f32_16x16x32_bf16(kl, b1h, a1, 0, 0, 0);
      }
      #pragma unroll
      for (int r = 0; r < 4; ++r) {
        o0[r] = fmaf(__half2float(gbuf[ch0][s][4 * hq + r][p]), a0[r], o0[r]);
        o1[r] = fmaf(__half2float(gbuf[ch1][s][4 * hq + r][p]), a1[r], o1[r]);
      }
    }

    const size_t obase = (size_t)b * TT * CC + c;
    #pragma unroll
    for (int r = 0; r < 4; ++r) {
      out[obase + (size_t)(256 * ch0 + 16 * p + 4 * hq + r) * CC] = o0[r];
      out[obase + (size_t)(256 * ch1 + 16 * p + 4 * hq + r) * CC] = o1[r];
    }
  }
}

extern "C" void kernel_launch(void* const* d_in, const int* in_sizes, int n_in,
                              void* d_out, int out_size, void* d_ws, size_t ws_size,
                              hipStream_t stream) {
  const float* x  = (const float*)d_in[0];
  const float* W1 = (const float*)d_in[1];
  const float* b1 = (const float*)d_in[2];
  const float* W2 = (const float*)d_in[3];
  const float* b2 = (const float*)d_in[4];
  const float* W3 = (const float*)d_in[5];
  const float* b3 = (const float*)d_in[6];
  float* outp = (float*)d_out;

  hipLaunchKernelGGL(init_frag, dim3(1), dim3(256), 0, stream, W2);
  hipLaunchKernelGGL(fused_main, dim3(BB * CC), dim3(256), 0, stream,
                     x, W1, b1, W2, b2, W3, b3, outp);
}

// Round 6
// 221.622 us; speedup vs baseline: 6.4574x; 1.4465x over previous
//
#include <hip/hip_runtime.h>
#include <hip/hip_fp16.h>
#include <math.h>

#define TT 2048
#define CC 64
#define BB 32
#define PAD 512
#define ROWL 3136          // padded bf16 row length

typedef __attribute__((ext_vector_type(8))) short short8;
typedef __attribute__((ext_vector_type(4))) float float4v;

// Toeplitz A-fragment tables: 67 K-steps x 64 lanes x 8 bf16 (hi/lo split)
#define NSTEPS 67
__device__ unsigned short g_afrag_hi[NSTEPS * 64 * 8];
__device__ unsigned short g_afrag_lo[NSTEPS * 64 * 8];

__device__ __forceinline__ float fast_rcp(float x) { return __builtin_amdgcn_rcpf(x); }
__device__ __forceinline__ float fast_exp2(float x) { return __builtin_amdgcn_exp2f(x); }
__device__ __forceinline__ float fast_log2(float x) { return __builtin_amdgcn_logf(x); }

__device__ __forceinline__ unsigned short f2bf(float x) {  // RNE bf16 round
  union { float f; unsigned u; } v; v.f = x;
  unsigned r = (v.u + 0x7FFFu + ((v.u >> 16) & 1u)) >> 16;
  return (unsigned short)r;
}
__device__ __forceinline__ float bf2f(unsigned short u) {
  union { unsigned u32; float f; } v; v.u32 = ((unsigned)u) << 16; return v.f;
}

// tanh-form GELU via sigmoid: x*sigma(1.595769x + 0.0713548x^3), max err ~4e-4
// exp(-s) = exp2(x*(-2.3020231 - 0.10294217*x^2))
__device__ __forceinline__ float gelu_f(float x) {
  float u = x * x;
  float w = x * fmaf(-0.10294217f, u, -2.3020231f);
  float e = fast_exp2(w);
  return x * fast_rcp(1.0f + e);
}

// ---- init: Gaussian taps -> Toeplitz MFMA fragments (grid-strided) ----
__global__ void init_frag() {
  __shared__ float ktap[2016];
  __shared__ double ssum[5];
  const int   Rr[5]  = {32, 64, 128, 256, 512};
  const float sg[5]  = {8.f, 16.f, 32.f, 64.f, 128.f};
  const int   off[5] = {0, 72, 208, 472, 984};
  const int tid = threadIdx.x;

  for (int idx = tid; idx < 2016; idx += 256) {
    int s = (idx < 72) ? 0 : (idx < 208) ? 1 : (idx < 472) ? 2 : (idx < 984) ? 3 : 4;
    int d = idx - off[s];
    float v = 0.f;
    if (d <= 2 * Rr[s]) {
      float n = (float)(d - Rr[s]) / sg[s];
      v = __expf(-0.5f * n * n);
    }
    ktap[idx] = v;
  }
  __syncthreads();
  if (tid < 5) {
    double sum = 0.0;
    for (int d = 0; d <= 2 * Rr[tid]; ++d) sum += (double)ktap[off[tid] + d];
    ssum[tid] = 1.0 / (sum + 1e-12);
  }
  __syncthreads();
  for (int idx = tid; idx < 2016; idx += 256) {
    int s = (idx < 72) ? 0 : (idx < 208) ? 1 : (idx < 472) ? 2 : (idx < 984) ? 3 : 4;
    ktap[idx] *= (float)ssum[s];
  }
  __syncthreads();

  const int cum[5] = {0, 3, 8, 17, 34};
  for (int e = blockIdx.x * 256 + tid; e < NSTEPS * 64; e += gridDim.x * 256) {
    int stg = e >> 6, lane = e & 63;
    int s = (stg < 3) ? 0 : (stg < 8) ? 1 : (stg < 17) ? 2 : (stg < 34) ? 3 : 4;
    int st = stg - cum[s];
    int i = lane & 15, h = lane >> 4;
    for (int e2 = 0; e2 < 8; ++e2) {
      int d = st * 32 + 8 * h + e2 - i;
      float v = (d >= 0 && d <= 2 * Rr[s]) ? ktap[off[s] + d] : 0.f;
      unsigned short hi = f2bf(v);
      g_afrag_hi[e * 8 + e2] = hi;
      g_afrag_lo[e * 8 + e2] = f2bf(v - bf2f(hi));
    }
  }
}

__launch_bounds__(256, 4)
__global__ void fused_main(const float* __restrict__ x,
                           const float* __restrict__ W1, const float* __restrict__ b1,
                           const float* __restrict__ W2, const float* __restrict__ b2,
                           const float* __restrict__ W3, const float* __restrict__ b3,
                           float* __restrict__ out) {
  __shared__ unsigned short row_hi[ROWL];
  __shared__ unsigned short row_lo[ROWL];
  __shared__ __half gbuf[8][5][16][20];   // gates; s=0..2 aliased as feats A1->A2

  const int tid = threadIdx.x;
  const int c = blockIdx.x & (CC - 1);
  const int b = blockIdx.x >> 6;
  const float* xrow = x + (size_t)b * TT * CC + c;

  // ---- stage reflect-padded row as bf16 hi/lo ----
  for (int i2 = tid; i2 < ROWL; i2 += 256) {
    int t = i2 - PAD;
    t = (t < 0) ? -t : t;
    t = (t >= TT) ? (2 * TT - 2 - t) : t;
    float xv = xrow[(size_t)t * CC];
    unsigned short hi = f2bf(xv);
    row_hi[i2] = hi;
    row_lo[i2] = f2bf(xv - bf2f(hi));
  }
  __syncthreads();

  const int t0 = tid * 8;
  const int lane = tid & 63;
  const int wvi = tid >> 6;

  // ======== Phase A1: sliding-window stats -> feats (to gbuf alias slots) ====
  {
    float w24[24];
    {
      const unsigned short* ph = &row_hi[PAD + t0 - 8];
      const unsigned short* pl = &row_lo[PAD + t0 - 8];
      unsigned hw[12], lw[12];
      *(uint4*)&hw[0] = *(const uint4*)ph;
      *(uint4*)&hw[4] = *(const uint4*)(ph + 8);
      *(uint4*)&hw[8] = *(const uint4*)(ph + 16);
      *(uint4*)&lw[0] = *(const uint4*)pl;
      *(uint4*)&lw[4] = *(const uint4*)(pl + 8);
      *(uint4*)&lw[8] = *(const uint4*)(pl + 16);
      #pragma unroll
      for (int m2 = 0; m2 < 12; ++m2) {
        union { unsigned u; float f; } a, bb, cc2, dd;
        a.u  = (hw[m2] & 0xFFFFu) << 16;  bb.u = hw[m2] & 0xFFFF0000u;
        cc2.u = (lw[m2] & 0xFFFFu) << 16; dd.u = lw[m2] & 0xFFFF0000u;
        w24[2 * m2]     = a.f + cc2.f;
        w24[2 * m2 + 1] = bb.f + dd.f;
      }
    }

    float sm = 0.f, sq = 0.f, scv = 0.f;
    #pragma unroll
    for (int j = 0; j < 16; ++j) {
      float v = w24[1 + j];
      sm += v;
      sq  = fmaf(v, v, sq);
      scv = fmaf(v, (float)j - 7.5f, scv);
    }

    #pragma unroll
    for (int i = 0; i < 8; ++i) {
      const float xv   = w24[i + 8];
      const float mean = sm * 0.0625f;
      const float ex2  = sq * 0.0625f;
      const float var  = fmaxf(ex2 - mean * mean, 0.f);
      const float slope = scv * (1.0f / 340.0f);
      const float stdv = sqrtf(var + 1e-6f);
      float z = (xv - mean) * fast_rcp(stdv);
      z = fminf(fmaxf(z, -10.f), 10.f);
      float lv = fast_log2(var + 1e-6f) * 0.069314718f;   // *ln2/10 = ln(.)/10
      float ns = slope * fast_rcp(stdv + 1e-6f);
      ns = fminf(fmaxf(ns, -10.f), 10.f);

      const int e = t0 + i;
      const int ch = e >> 8, rr = e & 15, pp = (e >> 4) & 15;
      gbuf[ch][0][rr][pp] = __float2half(z);
      gbuf[ch][1][rr][pp] = __float2half(lv);
      gbuf[ch][2][rr][pp] = __float2half(ns);

      if (i < 7) {   // slide window by one
        const float xo = w24[i + 1], xn = w24[i + 17];
        scv = fmaf(8.5f, xo, fmaf(7.5f, xn, scv - sm));
        sm += (xn - xo);
        sq = fmaf(xn, xn, sq);
        sq = fmaf(-xo, xo, sq);
      }
    }
  }

  // ======== Phase A2: wave-wide MLP via MFMA ========
  {
    const int kg = lane >> 4;        // k-group == row-quarter hq
    const int m  = lane & 15;        // element column

    // W2 A-fragments (hi/lo) built in-register from global W2
    short8 w2h0, w2l0, w2h1, w2l1;
    {
      const float* p0 = W2 + (size_t)m * 32 + 8 * kg;
      const float* p1 = W2 + (size_t)(16 + m) * 32 + 8 * kg;
      #pragma unroll
      for (int e2 = 0; e2 < 8; ++e2) {
        float v0 = p0[e2], v1 = p1[e2];
        unsigned short h0 = f2bf(v0);
        w2h0[e2] = (short)h0; w2l0[e2] = (short)f2bf(v0 - bf2f(h0));
        unsigned short h1v = f2bf(v1);
        w2h1[e2] = (short)h1v; w2l1[e2] = (short)f2bf(v1 - bf2f(h1v));
      }
    }

    float4v w1q[6], b1q2[2], b2a, b2b, w3A[5], w3B[5];
    #pragma unroll
    for (int k = 0; k < 6; ++k) w1q[k] = *(const float4v*)(W1 + 24 * kg + 4 * k);
    b1q2[0] = *(const float4v*)(b1 + 8 * kg);
    b1q2[1] = *(const float4v*)(b1 + 8 * kg + 4);
    b2a = *(const float4v*)(b2 + 4 * kg);
    b2b = *(const float4v*)(b2 + 16 + 4 * kg);
    #pragma unroll
    for (int k = 0; k < 5; ++k) {
      w3A[k] = *(const float4v*)(W3 + 32 * k + 4 * kg);
      w3B[k] = *(const float4v*)(W3 + 32 * k + 16 + 4 * kg);
    }
    const float b30 = b3[0], b31 = b3[1], b32 = b3[2], b33 = b3[3], b34 = b3[4];
    const float kS = 2.0609929f;     // log2(e)/0.7

    #pragma unroll 1
    for (int j = 0; j < 32; ++j) {
      const int ch = 2 * wvi + (j >> 4);
      const int pp = j & 15;

      // features of column element m
      float z  = __half2float(gbuf[ch][0][m][pp]);
      float lv = __half2float(gbuf[ch][1][m][pp]);
      float ns = __half2float(gbuf[ch][2][m][pp]);

      // layer 1 in B-fragment layout: 8 neurons (k = 8*kg + e2) of column m
      short8 bfr;
      #pragma unroll
      for (int e2 = 0; e2 < 8; ++e2) {
        float p = b1q2[e2 >> 2][e2 & 3];
        p = fmaf(w1q[(3*e2)   >> 2][(3*e2)   & 3], z,  p);
        p = fmaf(w1q[(3*e2+1) >> 2][(3*e2+1) & 3], lv, p);
        p = fmaf(w1q[(3*e2+2) >> 2][(3*e2+2) & 3], ns, p);
        bfr[e2] = (short)f2bf(gelu_f(p));
      }

      // layer 2: h2pre = W2 * h1  (2 g-tiles, W2 hi/lo 2-pass)
      float4v acc0 = {0.f,0.f,0.f,0.f}, acc1 = {0.f,0.f,0.f,0.f};
      acc0 = __builtin_amdgcn_mfma_f32_16x16x32_bf16(w2h0, bfr, acc0, 0, 0, 0);
      acc0 = __builtin_amdgcn_mfma_f32_16x16x32_bf16(w2l0, bfr, acc0, 0, 0, 0);
      acc1 = __builtin_amdgcn_mfma_f32_16x16x32_bf16(w2h1, bfr, acc1, 0, 0, 0);
      acc1 = __builtin_amdgcn_mfma_f32_16x16x32_bf16(w2l1, bfr, acc1, 0, 0, 0);

      // bias + GELU + W3 partial dot (rows g = 16gt + 4kg + r)
      float lg0 = 0.f, lg1 = 0.f, lg2 = 0.f, lg3 = 0.f, lg4 = 0.f;
      #pragma unroll
      for (int r = 0; r < 4; ++r) {
        float ha = gelu_f(acc0[r] + b2a[r]);
        float hb = gelu_f(acc1[r] + b2b[r]);
        lg0 = fmaf(w3A[0][r], ha, lg0); lg0 = fmaf(w3B[0][r], hb, lg0);
        lg1 = fmaf(w3A[1][r], ha, lg1); lg1 = fmaf(w3B[1][r], hb, lg1);
        lg2 = fmaf(w3A[2][r], ha, lg2); lg2 = fmaf(w3B[2][r], hb, lg2);
        lg3 = fmaf(w3A[3][r], ha, lg3); lg3 = fmaf(w3B[3][r], hb, lg3);
        lg4 = fmaf(w3A[4][r], ha, lg4); lg4 = fmaf(w3B[4][r], hb, lg4);
      }
      // reduce across the 4 row-quarters (lanes m, m+16, m+32, m+48)
      lg0 += __shfl_xor(lg0, 16); lg0 += __shfl_xor(lg0, 32);
      lg1 += __shfl_xor(lg1, 16); lg1 += __shfl_xor(lg1, 32);
      lg2 += __shfl_xor(lg2, 16); lg2 += __shfl_xor(lg2, 32);
      lg3 += __shfl_xor(lg3, 16); lg3 += __shfl_xor(lg3, 32);
      lg4 += __shfl_xor(lg4, 16); lg4 += __shfl_xor(lg4, 32);
      lg0 += b30; lg1 += b31; lg2 += b32; lg3 += b33; lg4 += b34;

      // softmax(logits/0.7) via exp2 with folded scale
      const float mx = fmaxf(fmaxf(fmaxf(lg0, lg1), fmaxf(lg2, lg3)), lg4);
      const float mxs = mx * kS;
      float e0 = fast_exp2(fmaf(lg0, kS, -mxs));
      float e1 = fast_exp2(fmaf(lg1, kS, -mxs));
      float e2 = fast_exp2(fmaf(lg2, kS, -mxs));
      float e3 = fast_exp2(fmaf(lg3, kS, -mxs));
      float e4 = fast_exp2(fmaf(lg4, kS, -mxs));
      const float rs = fast_rcp(e0 + e1 + e2 + e3 + e4);

      // each quarter writes its own scale slot; quarter 0 also writes s=4
      float gw = e0;
      gw = (kg == 1) ? e1 : gw;
      gw = (kg == 2) ? e2 : gw;
      gw = (kg == 3) ? e3 : gw;
      gbuf[ch][kg][m][pp] = __float2half(gw * rs);
      if (kg == 0) gbuf[ch][4][m][pp] = __float2half(e4 * rs);
    }
  }
  // gates produced & consumed by the same wave -> no barrier needed

  // ======== Phase B: Toeplitz-MFMA conv (3-pass hi/lo) + gated combine ====
  {
    const int hq = lane >> 4, p = lane & 15;
    const int ch0 = 2 * wvi, ch1 = 2 * wvi + 1;

    const int Rs[5]    = {32, 64, 128, 256, 512};
    const int steps[5] = {3, 5, 9, 17, 33};
    const int cum[5]   = {0, 3, 8, 17, 34};

    float4v o0 = {0.f,0.f,0.f,0.f}, o1 = {0.f,0.f,0.f,0.f};

    #pragma unroll 1
    for (int s = 0; s < 5; ++s) {
      float4v a0 = {0.f,0.f,0.f,0.f}, a1 = {0.f,0.f,0.f,0.f};
      const int eb0 = PAD + 256 * ch0 - Rs[s] + 16 * p + 8 * hq;
      const int eb1 = eb0 + 256;
      const unsigned short* ahb = g_afrag_hi + (size_t)cum[s] * 512 + lane * 8;
      const unsigned short* alb = g_afrag_lo + (size_t)cum[s] * 512 + lane * 8;

      for (int st = 0; st < steps[s]; ++st) {
        short8 kh = *(const short8*)(ahb + st * 512);
        short8 kl = *(const short8*)(alb + st * 512);
        short8 b0h = *(const short8*)(&row_hi[eb0 + st * 32]);
        short8 b0l = *(const short8*)(&row_lo[eb0 + st * 32]);
        short8 b1h = *(const short8*)(&row_hi[eb1 + st * 32]);
        short8 b1l = *(const short8*)(&row_lo[eb1 + st * 32]);
        a0 = __builtin_amdgcn_mfma_f32_16x16x32_bf16(kh, b0h, a0, 0, 0, 0);
        a0 = __builtin_amdgcn_mfma_f32_16x16x32_bf16(kh, b0l, a0, 0, 0, 0);
        a0 = __builtin_amdgcn_mfma_f32_16x16x32_bf16(kl, b0h, a0, 0, 0, 0);
        a1 = __builtin_amdgcn_mfma_f32_16x16x32_bf16(kh, b1h, a1, 0, 0, 0);
        a1 = __builtin_amdgcn_mfma_f32_16x16x32_bf16(kh, b1l, a1, 0, 0, 0);
        a1 = __builtin_amdgcn_mfma_f32_16x16x32_bf16(kl, b1h, a1, 0, 0, 0);
      }
      #pragma unroll
      for (int r = 0; r < 4; ++r) {
        o0[r] = fmaf(__half2float(gbuf[ch0][s][4 * hq + r][p]), a0[r], o0[r]);
        o1[r] = fmaf(__half2float(gbuf[ch1][s][4 * hq + r][p]), a1[r], o1[r]);
      }
    }

    const size_t obase = (size_t)b * TT * CC + c;
    #pragma unroll
    for (int r = 0; r < 4; ++r) {
      out[obase + (size_t)(256 * ch0 + 16 * p + 4 * hq + r) * CC] = o0[r];
      out[obase + (size_t)(256 * ch1 + 16 * p + 4 * hq + r) * CC] = o1[r];
    }
  }
}

extern "C" void kernel_launch(void* const* d_in, const int* in_sizes, int n_in,
                              void* d_out, int out_size, void* d_ws, size_t ws_size,
                              hipStream_t stream) {
  const float* x  = (const float*)d_in[0];
  const float* W1 = (const float*)d_in[1];
  const float* b1 = (const float*)d_in[2];
  const float* W2 = (const float*)d_in[3];
  const float* b2 = (const float*)d_in[4];
  const float* W3 = (const float*)d_in[5];
  const float* b3 = (const float*)d_in[6];
  float* outp = (float*)d_out;

  hipLaunchKernelGGL(init_frag, dim3(8), dim3(256), 0, stream);
  hipLaunchKernelGGL(fused_main, dim3(BB * CC), dim3(256), 0, stream,
                     x, W1, b1, W2, b2, W3, b3, outp);
}